// Round 1
// baseline (524.366 us; speedup 1.0000x reference)
//
#include <hip/hip_runtime.h>

namespace {
constexpr unsigned kT  = 1u << 19;
constexpr unsigned kTm = kT - 1u;
constexpr unsigned kP1 = 2654435761u;
constexpr unsigned kP2 = 805459861u;
}

__global__ __launch_bounds__(256) void hashgrid_fwd(
    const float* __restrict__ x,
    const float* __restrict__ hashmap,
    const float* __restrict__ resolution,
    float2* __restrict__ out,
    int npts)
{
    int t = blockIdx.x * 256 + threadIdx.x;
    int n = t >> 4;   // point index
    int l = t & 15;   // level index
    if (n >= npts) return;

    float px = x[3*n+0], py = x[3*n+1], pz = x[3*n+2];
    float res = resolution[l];

    float xs = px*res, ys = py*res, zs = pz*res;
    float fx = floorf(xs), fy = floorf(ys), fz = floorf(zs);
    float wx = xs-fx, wy = ys-fy, wz = zs-fz;

    unsigned cx0 = (unsigned)fx;
    unsigned cy0 = (unsigned)fy;
    unsigned cz0 = (unsigned)fz;
    unsigned hx0 = cx0,          hx1 = cx0 + 1u;
    unsigned hy0 = cy0 * kP1,    hy1 = (cy0 + 1u) * kP1;
    unsigned hz0 = cz0 * kP2,    hz1 = (cz0 + 1u) * kP2;

    const float2* __restrict__ tb =
        reinterpret_cast<const float2*>(hashmap) + (size_t)l * kT;

    unsigned i000 = (hx0 ^ hy0 ^ hz0) & kTm;
    unsigned i001 = (hx0 ^ hy0 ^ hz1) & kTm;
    unsigned i010 = (hx0 ^ hy1 ^ hz0) & kTm;
    unsigned i011 = (hx0 ^ hy1 ^ hz1) & kTm;
    unsigned i100 = (hx1 ^ hy0 ^ hz0) & kTm;
    unsigned i101 = (hx1 ^ hy0 ^ hz1) & kTm;
    unsigned i110 = (hx1 ^ hy1 ^ hz0) & kTm;
    unsigned i111 = (hx1 ^ hy1 ^ hz1) & kTm;

    float2 f000 = tb[i000];
    float2 f001 = tb[i001];
    float2 f010 = tb[i010];
    float2 f011 = tb[i011];
    float2 f100 = tb[i100];
    float2 f101 = tb[i101];
    float2 f110 = tb[i110];
    float2 f111 = tb[i111];

    float wxn = 1.f - wx, wyn = 1.f - wy, wzn = 1.f - wz;
    float w000 = wxn*wyn*wzn, w001 = wxn*wyn*wz;
    float w010 = wxn*wy *wzn, w011 = wxn*wy *wz;
    float w100 = wx *wyn*wzn, w101 = wx *wyn*wz;
    float w110 = wx *wy *wzn, w111 = wx *wy *wz;

    float o0 = w000*f000.x + w001*f001.x + w010*f010.x + w011*f011.x
             + w100*f100.x + w101*f101.x + w110*f110.x + w111*f111.x;
    float o1 = w000*f000.y + w001*f001.y + w010*f010.y + w011*f011.y
             + w100*f100.y + w101*f101.y + w110*f110.y + w111*f111.y;

    out[(size_t)n*16 + l] = make_float2(o0, o1);
}

extern "C" void kernel_launch(void* const* d_in, const int* in_sizes, int n_in,
                              void* d_out, int out_size, void* d_ws, size_t ws_size,
                              hipStream_t stream) {
    const float* x          = (const float*)d_in[0];
    const float* hashmap    = (const float*)d_in[1];
    const float* resolution = (const float*)d_in[2];
    float2* out = (float2*)d_out;

    int npts  = in_sizes[0] / 3;
    int total = npts * 16;
    int blocks = (total + 255) / 256;
    hashgrid_fwd<<<blocks, 256, 0, stream>>>(x, hashmap, resolution, out, npts);
}

// Round 2
// 351.008 us; speedup vs baseline: 1.4939x; 1.4939x over previous
//
#include <hip/hip_runtime.h>

namespace {
constexpr unsigned kT  = 1u << 19;
constexpr unsigned kTm = kT - 1u;
constexpr unsigned kP1 = 2654435761u;
constexpr unsigned kP2 = 805459861u;
}

typedef float f32x2 __attribute__((ext_vector_type(2)));

// One block = 256 points at ONE level. blockIdx layout gives XCD<->level
// affinity under round-robin dispatch (block i -> XCD i%8):
//   g = i % 8, j = i / 8, phase = j / cpl, level = g + 8*phase, chunk = j % cpl
// so XCD g streams level g's whole 4 MiB table (L2-resident), then level g+8.
__global__ __launch_bounds__(256) void hashgrid_fwd_lvl(
    const float* __restrict__ x,
    const float* __restrict__ hashmap,
    const float* __restrict__ resolution,
    f32x2* __restrict__ out,
    int npts, unsigned cpl)
{
    unsigned i = blockIdx.x;
    unsigned g = i & 7u;
    unsigned j = i >> 3;
    unsigned phase = j / cpl;          // uniform scalar division, once/block
    unsigned chunk = j - phase * cpl;
    unsigned l = g + (phase << 3);

    int n = (int)(chunk * 256u + threadIdx.x);
    if (n >= npts) return;

    // x rows: 768 B contiguous per wave -> coalesced; nt (no reuse on this XCD soon)
    float px = __builtin_nontemporal_load(&x[3*n+0]);
    float py = __builtin_nontemporal_load(&x[3*n+1]);
    float pz = __builtin_nontemporal_load(&x[3*n+2]);
    float res = resolution[l];         // uniform -> scalar load

    float xs = px*res, ys = py*res, zs = pz*res;
    float fx = floorf(xs), fy = floorf(ys), fz = floorf(zs);
    float wx = xs-fx, wy = ys-fy, wz = zs-fz;

    unsigned cx0 = (unsigned)fx;
    unsigned cy0 = (unsigned)fy;
    unsigned cz0 = (unsigned)fz;
    unsigned hx0 = cx0,          hx1 = cx0 + 1u;
    unsigned hy0 = cy0 * kP1,    hy1 = (cy0 + 1u) * kP1;
    unsigned hz0 = cz0 * kP2,    hz1 = (cz0 + 1u) * kP2;

    const f32x2* __restrict__ tb =
        reinterpret_cast<const f32x2*>(hashmap) + (size_t)l * kT;

    unsigned i000 = (hx0 ^ hy0 ^ hz0) & kTm;
    unsigned i001 = (hx0 ^ hy0 ^ hz1) & kTm;
    unsigned i010 = (hx0 ^ hy1 ^ hz0) & kTm;
    unsigned i011 = (hx0 ^ hy1 ^ hz1) & kTm;
    unsigned i100 = (hx1 ^ hy0 ^ hz0) & kTm;
    unsigned i101 = (hx1 ^ hy0 ^ hz1) & kTm;
    unsigned i110 = (hx1 ^ hy1 ^ hz0) & kTm;
    unsigned i111 = (hx1 ^ hy1 ^ hz1) & kTm;

    f32x2 f000 = tb[i000];
    f32x2 f001 = tb[i001];
    f32x2 f010 = tb[i010];
    f32x2 f011 = tb[i011];
    f32x2 f100 = tb[i100];
    f32x2 f101 = tb[i101];
    f32x2 f110 = tb[i110];
    f32x2 f111 = tb[i111];

    float wxn = 1.f - wx, wyn = 1.f - wy, wzn = 1.f - wz;
    float w000 = wxn*wyn*wzn, w001 = wxn*wyn*wz;
    float w010 = wxn*wy *wzn, w011 = wxn*wy *wz;
    float w100 = wx *wyn*wzn, w101 = wx *wyn*wz;
    float w110 = wx *wy *wzn, w111 = wx *wy *wz;

    f32x2 o;
    o.x = w000*f000.x + w001*f001.x + w010*f010.x + w011*f011.x
        + w100*f100.x + w101*f101.x + w110*f110.x + w111*f111.x;
    o.y = w000*f000.y + w001*f001.y + w010*f010.y + w011*f011.y
        + w100*f100.y + w101*f101.y + w110*f110.y + w111*f111.y;

    // strided (128 B/lane) store; nt so write lines don't evict the level table
    __builtin_nontemporal_store(o, &out[(size_t)n*16 + l]);
}

extern "C" void kernel_launch(void* const* d_in, const int* in_sizes, int n_in,
                              void* d_out, int out_size, void* d_ws, size_t ws_size,
                              hipStream_t stream) {
    const float* x          = (const float*)d_in[0];
    const float* hashmap    = (const float*)d_in[1];
    const float* resolution = (const float*)d_in[2];
    f32x2* out = (f32x2*)d_out;

    int npts = in_sizes[0] / 3;
    unsigned cpl = (unsigned)((npts + 255) / 256);   // chunks per level
    unsigned blocks = 16u * cpl;                     // 16 levels
    hashgrid_fwd_lvl<<<blocks, 256, 0, stream>>>(x, hashmap, resolution, out,
                                                 npts, cpl);
}